// Round 5
// baseline (456.835 us; speedup 1.0000x reference)
//
#include <hip/hip_runtime.h>

#define N_I 500000
#define N_H 200000
#define E1  2000000
#define E2  2000000
#define TOTAL_E (E1 + E2)

#define NB 512                      // buckets (dst >> 10); 489 used
#define CHUNK 2048                  // edges per workgroup (hist/scatter)
#define NWG ((TOTAL_E + CHUNK - 1) / CHUNK)   // = 1954
#define NB_RED ((N_I + 1023) / 1024)          // = 489 reduce blocks
#define WPT 8                       // H entries per thread in scan_cols

// ---------------------------------------------------------------------------
// Per-node precompute: g[n, 0:8] = x[n]^T @ W_edge, g[n,8] = dot(x[n], b_edge)
// stride 12 floats. ROOT: out[n] = dot(x[n], Wr1+Wr2) + rb1 + rb2.
// ---------------------------------------------------------------------------
template<int F, bool ROOT>
__global__ __launch_bounds__(256) void precompute_g(
    const float* __restrict__ x, const float* __restrict__ W, const float* __restrict__ b,
    float* __restrict__ g, int n,
    const float* __restrict__ rW1, const float* __restrict__ rW2,
    const float* __restrict__ rb1, const float* __restrict__ rb2,
    float* __restrict__ out)
{
    __shared__ float Wf[F * 8];
    __shared__ float bv[F];
    __shared__ float wr[F];

    for (int i = threadIdx.x; i < F * 8; i += 256) Wf[i] = W[i];
    if (threadIdx.x < F) {
        bv[threadIdx.x] = b[threadIdx.x];
        if (ROOT) wr[threadIdx.x] = rW1[threadIdx.x] + rW2[threadIdx.x];
    }
    __syncthreads();

    int nid = blockIdx.x * 256 + threadIdx.x;
    if (nid >= n) return;

    float xv[F];
    const float4* xp = (const float4*)(x + (size_t)nid * F);
    #pragma unroll
    for (int q = 0; q < F / 4; q++) {
        float4 v = xp[q];
        xv[q*4+0] = v.x; xv[q*4+1] = v.y; xv[q*4+2] = v.z; xv[q*4+3] = v.w;
    }

    float acc[9];
    #pragma unroll
    for (int k = 0; k < 9; k++) acc[k] = 0.f;

    #pragma unroll
    for (int j = 0; j < F; j++) {
        float4 w0 = *(const float4*)(Wf + j * 8);
        float4 w1 = *(const float4*)(Wf + j * 8 + 4);
        float xj = xv[j];
        acc[0] = fmaf(xj, w0.x, acc[0]);
        acc[1] = fmaf(xj, w0.y, acc[1]);
        acc[2] = fmaf(xj, w0.z, acc[2]);
        acc[3] = fmaf(xj, w0.w, acc[3]);
        acc[4] = fmaf(xj, w1.x, acc[4]);
        acc[5] = fmaf(xj, w1.y, acc[5]);
        acc[6] = fmaf(xj, w1.z, acc[6]);
        acc[7] = fmaf(xj, w1.w, acc[7]);
        acc[8] = fmaf(xj, bv[j], acc[8]);
    }

    float4* gp = (float4*)(g + (size_t)nid * 12);
    gp[0] = make_float4(acc[0], acc[1], acc[2], acc[3]);
    gp[1] = make_float4(acc[4], acc[5], acc[6], acc[7]);
    gp[2] = make_float4(acc[8], 0.f, 0.f, 0.f);

    if (ROOT) {
        float r = rb1[0] + rb2[0];
        #pragma unroll
        for (int j = 0; j < F; j++) r = fmaf(xv[j], wr[j], r);
        out[nid] = r;
    }
}

// ---------------------------------------------------------------------------
// Kernel A: per-WG dst-bucket histogram. 8 contiguous dsts/thread via int4.
// ---------------------------------------------------------------------------
__global__ __launch_bounds__(256) void hist_kernel(
    const int* __restrict__ dst1, const int* __restrict__ dst2,
    int* __restrict__ H)
{
    __shared__ int hist[NB];
    for (int i = threadIdx.x; i < NB; i += 256) hist[i] = 0;
    __syncthreads();

    int t0 = blockIdx.x * CHUNK + threadIdx.x * 8;
    if (t0 < TOTAL_E) {   // TOTAL_E % 8 == 0 -> all-or-nothing
        const int* dp = (t0 < E1) ? (dst1 + t0) : (dst2 + (t0 - E1));
        int4 d0 = *(const int4*)dp;
        int4 d1 = *(const int4*)(dp + 4);
        atomicAdd(&hist[d0.x >> 10], 1);
        atomicAdd(&hist[d0.y >> 10], 1);
        atomicAdd(&hist[d0.z >> 10], 1);
        atomicAdd(&hist[d0.w >> 10], 1);
        atomicAdd(&hist[d1.x >> 10], 1);
        atomicAdd(&hist[d1.y >> 10], 1);
        atomicAdd(&hist[d1.z >> 10], 1);
        atomicAdd(&hist[d1.w >> 10], 1);
    }
    __syncthreads();
    for (int i = threadIdx.x; i < NB; i += 256) H[blockIdx.x * NB + i] = hist[i];
}

// Kernel B: per bucket b, exclusive scan of H[w][b] over w, in place.
__global__ __launch_bounds__(256) void scan_cols_kernel(int* __restrict__ H,
                                                        int* __restrict__ total)
{
    __shared__ int sums[256];
    int b = blockIdx.x;
    int tid = threadIdx.x;

    int vals[WPT];
    int s = 0;
    #pragma unroll
    for (int k = 0; k < WPT; k++) {
        int w = tid * WPT + k;
        vals[k] = (w < NWG) ? H[w * NB + b] : 0;
        s += vals[k];
    }
    sums[tid] = s;
    __syncthreads();
    for (int off = 1; off < 256; off <<= 1) {
        int t = (tid >= off) ? sums[tid - off] : 0;
        __syncthreads();
        sums[tid] += t;
        __syncthreads();
    }
    int run = sums[tid] - s;
    #pragma unroll
    for (int k = 0; k < WPT; k++) {
        int w = tid * WPT + k;
        if (w < NWG) H[w * NB + b] = run;
        run += vals[k];
    }
    if (tid == 255) total[b] = sums[255];
}

// Kernel C: exclusive scan of bucket totals -> base.
__global__ __launch_bounds__(512) void scan_base_kernel(const int* __restrict__ total,
                                                        int* __restrict__ base)
{
    __shared__ int v[512];
    int tid = threadIdx.x;
    int orig = total[tid];
    v[tid] = orig;
    __syncthreads();
    for (int off = 1; off < 512; off <<= 1) {
        int t = (tid >= off) ? v[tid - off] : 0;
        __syncthreads();
        v[tid] += t;
        __syncthreads();
    }
    base[tid] = v[tid] - orig;
}

// ---------------------------------------------------------------------------
// Kernel E: fused msg-compute + scatter, 8 edges/thread (2 batches of 4).
// All idx loads issued up-front; per batch 20 independent gather loads in
// flight before any FMA -> high MLP to hide HBM/L3 gather latency.
// ---------------------------------------------------------------------------
__global__ __launch_bounds__(256) void scatter_msg_kernel(
    const int* __restrict__ src1, const int* __restrict__ dst1,
    const float* __restrict__ ea1, const float* __restrict__ g1,
    const int* __restrict__ src2, const int* __restrict__ dst2,
    const float* __restrict__ ea2, const float* __restrict__ g2,
    const int* __restrict__ H, const int* __restrict__ base,
    uint2* __restrict__ pairs)
{
    __shared__ int cur[NB];
    for (int i = threadIdx.x; i < NB; i += 256)
        cur[i] = H[blockIdx.x * NB + i] + base[i];
    __syncthreads();

    int t0 = blockIdx.x * CHUNK + threadIdx.x * 8;
    if (t0 < TOTAL_E) {   // TOTAL_E % 8 == 0, E1 % 8 == 0 -> no straddle
        int e0;
        const int* srcp; const int* dstp; const float* eap; const float* gp;
        if (t0 < E1) { e0 = t0;      srcp = src1; dstp = dst1; eap = ea1; gp = g1; }
        else         { e0 = t0 - E1; srcp = src2; dstp = dst2; eap = ea2; gp = g2; }

        // all 8 src + 8 dst up-front (coalesced int4)
        int4 s0 = *(const int4*)(srcp + e0);
        int4 s1 = *(const int4*)(srcp + e0 + 4);
        int4 d0 = *(const int4*)(dstp + e0);
        int4 d1 = *(const int4*)(dstp + e0 + 4);
        int ss[8] = {s0.x, s0.y, s0.z, s0.w, s1.x, s1.y, s1.z, s1.w};
        int dd[8] = {d0.x, d0.y, d0.z, d0.w, d1.x, d1.y, d1.z, d1.w};

        #pragma unroll
        for (int half = 0; half < 2; ++half) {
            float4 a0[4], a1[4], ga[4], gb[4], gc[4];
            #pragma unroll
            for (int j = 0; j < 4; j++) {
                int e = e0 + half * 4 + j;
                const float4* ap = (const float4*)(eap + (size_t)e * 8);
                a0[j] = ap[0];
                a1[j] = ap[1];
                const float4* gr = (const float4*)(gp + (size_t)ss[half * 4 + j] * 12);
                ga[j] = gr[0];
                gb[j] = gr[1];
                gc[j] = gr[2];
            }
            #pragma unroll
            for (int j = 0; j < 4; j++) {
                float msg = gc[j].x;
                msg = fmaf(a0[j].x, ga[j].x, msg);
                msg = fmaf(a0[j].y, ga[j].y, msg);
                msg = fmaf(a0[j].z, ga[j].z, msg);
                msg = fmaf(a0[j].w, ga[j].w, msg);
                msg = fmaf(a1[j].x, gb[j].x, msg);
                msg = fmaf(a1[j].y, gb[j].y, msg);
                msg = fmaf(a1[j].z, gb[j].z, msg);
                msg = fmaf(a1[j].w, gb[j].w, msg);
                int d = dd[half * 4 + j];
                int pos = atomicAdd(&cur[d >> 10], 1);
                pairs[pos] = make_uint2((unsigned)d, __float_as_uint(msg));
            }
        }
    }
}

// Kernel F: per-bucket reduction in LDS, then one coalesced out +=.
__global__ __launch_bounds__(1024) void reduce_kernel(
    const uint2* __restrict__ pairs, const int* __restrict__ base,
    const int* __restrict__ total, float* __restrict__ out)
{
    __shared__ float acc[1024];
    acc[threadIdx.x] = 0.f;
    __syncthreads();

    int b = blockIdx.x;
    int start = base[b];
    int cnt = total[b];
    // 2 pairs per iteration for a little MLP
    int i = threadIdx.x * 2;
    int stride = 2048;
    for (; i + 1 < cnt; i += stride) {
        uint2 p0 = pairs[start + i];
        uint2 p1 = pairs[start + i + 1];
        atomicAdd(&acc[p0.x & 1023], __uint_as_float(p0.y));
        atomicAdd(&acc[p1.x & 1023], __uint_as_float(p1.y));
    }
    if (i < cnt) {
        uint2 p = pairs[start + i];
        atomicAdd(&acc[p.x & 1023], __uint_as_float(p.y));
    }
    __syncthreads();

    int n = (b << 10) + threadIdx.x;
    if (n < N_I) out[n] += acc[threadIdx.x];
}

// ---------------------------------------------------------------------------
// Fallback: round-2 atomic edge kernel (used only if ws too small).
// ---------------------------------------------------------------------------
__global__ __launch_bounds__(256) void edge_kernel_atomic(
    const int* __restrict__ src1, const int* __restrict__ dst1,
    const float* __restrict__ ea1, const float* __restrict__ g1,
    const int* __restrict__ src2, const int* __restrict__ dst2,
    const float* __restrict__ ea2, const float* __restrict__ g2,
    float* __restrict__ out)
{
    int t = blockIdx.x * 256 + threadIdx.x;
    if (t >= TOTAL_E) return;
    const int* srcp; const int* dstp; const float* eap; const float* gp;
    int e;
    if (t < E1) { e = t;      srcp = src1; dstp = dst1; eap = ea1; gp = g1; }
    else        { e = t - E1; srcp = src2; dstp = dst2; eap = ea2; gp = g2; }
    int s = srcp[e];
    int d = dstp[e];
    const float4* ap = (const float4*)(eap + (size_t)e * 8);
    float4 a0 = ap[0];
    float4 a1 = ap[1];
    const float4* gr = (const float4*)(gp + (size_t)s * 12);
    float4 ga = gr[0];
    float4 gb = gr[1];
    float4 gc = gr[2];
    float msg = gc.x;
    msg = fmaf(a0.x, ga.x, msg);
    msg = fmaf(a0.y, ga.y, msg);
    msg = fmaf(a0.z, ga.z, msg);
    msg = fmaf(a0.w, ga.w, msg);
    msg = fmaf(a1.x, gb.x, msg);
    msg = fmaf(a1.y, gb.y, msg);
    msg = fmaf(a1.z, gb.z, msg);
    msg = fmaf(a1.w, gb.w, msg);
    atomicAdd(out + d, msg);
}

extern "C" void kernel_launch(void* const* d_in, const int* in_sizes, int n_in,
                              void* d_out, int out_size, void* d_ws, size_t ws_size,
                              hipStream_t stream) {
    const float* x_i  = (const float*)d_in[0];
    const float* x_h  = (const float*)d_in[1];
    const float* ea_h = (const float*)d_in[2];
    const float* ea_i = (const float*)d_in[3];
    const float* We_h = (const float*)d_in[4];
    const float* be_h = (const float*)d_in[5];
    const float* We_i = (const float*)d_in[6];
    const float* be_i = (const float*)d_in[7];
    const float* Wr_h = (const float*)d_in[8];
    const float* br_h = (const float*)d_in[9];
    const float* Wr_i = (const float*)d_in[10];
    const float* br_i = (const float*)d_in[11];
    const int* src_h = (const int*)d_in[12];
    const int* dst_h = (const int*)d_in[13];
    const int* src_i = (const int*)d_in[14];
    const int* dst_i = (const int*)d_in[15];

    float* out = (float*)d_out;

    // workspace layout (g live through scatter -> pairs must NOT alias g)
    char* ws = (char*)d_ws;
    float* g_i   = (float*)ws;                     // 24,000,000 B
    float* g_h   = (float*)(ws + 24000000);        //  9,600,000 B
    uint2* pairs = (uint2*)(ws + 33600000);        // 32,000,000 B
    int*   H     = (int*)  (ws + 65600000);        //  4,001,792 B (1954*512*4)
    int*   tot   = (int*)  (ws + 69601792);        //      2,048 B
    int*   bas   = (int*)  (ws + 69603840);        //      2,048 B
    const size_t WS_NEEDED = 69605888;             // ~69.6 MB

    precompute_g<16, false><<<(N_H + 255) / 256, 256, 0, stream>>>(
        x_h, We_h, be_h, g_h, N_H, nullptr, nullptr, nullptr, nullptr, nullptr);
    precompute_g<32, true><<<(N_I + 255) / 256, 256, 0, stream>>>(
        x_i, We_i, be_i, g_i, N_I, Wr_h, Wr_i, br_h, br_i, out);

    if (ws_size >= WS_NEEDED) {
        hist_kernel<<<NWG, 256, 0, stream>>>(dst_h, dst_i, H);
        scan_cols_kernel<<<NB, 256, 0, stream>>>(H, tot);
        scan_base_kernel<<<1, 512, 0, stream>>>(tot, bas);
        scatter_msg_kernel<<<NWG, 256, 0, stream>>>(
            src_h, dst_h, ea_h, g_h, src_i, dst_i, ea_i, g_i, H, bas, pairs);
        reduce_kernel<<<NB_RED, 1024, 0, stream>>>(pairs, bas, tot, out);
    } else {
        edge_kernel_atomic<<<(TOTAL_E + 255) / 256, 256, 0, stream>>>(
            src_h, dst_h, ea_h, g_h, src_i, dst_i, ea_i, g_i, out);
    }
}

// Round 6
// 369.466 us; speedup vs baseline: 1.2365x; 1.2365x over previous
//
#include <hip/hip_runtime.h>

#define N_I 500000
#define N_H 200000
#define E1  2000000
#define E2  2000000
#define TOTAL_E (E1 + E2)

#define BSHIFT 12                   // bucket = dst >> 12 (4096 nodes/bucket)
#define NB 128                      // allocated buckets; 123 used
#define NBK ((N_I + 4095) / 4096)   // = 123 used buckets
#define CHUNK 2048                  // edges per workgroup (msg_hist/scatter)
#define NWG ((TOTAL_E + CHUNK - 1) / CHUNK)   // = 1954
#define WPT 8                       // H entries per thread in scan_cols

// ---------------------------------------------------------------------------
// Per-node precompute: g[n, 0:8] = x[n]^T @ W_edge, g[n,8] = dot(x[n], b_edge)
// stride 12 floats. ROOT: out[n] = dot(x[n], Wr1+Wr2) + rb1 + rb2.
// ---------------------------------------------------------------------------
template<int F, bool ROOT>
__global__ __launch_bounds__(256) void precompute_g(
    const float* __restrict__ x, const float* __restrict__ W, const float* __restrict__ b,
    float* __restrict__ g, int n,
    const float* __restrict__ rW1, const float* __restrict__ rW2,
    const float* __restrict__ rb1, const float* __restrict__ rb2,
    float* __restrict__ out)
{
    __shared__ float Wf[F * 8];
    __shared__ float bv[F];
    __shared__ float wr[F];

    for (int i = threadIdx.x; i < F * 8; i += 256) Wf[i] = W[i];
    if (threadIdx.x < F) {
        bv[threadIdx.x] = b[threadIdx.x];
        if (ROOT) wr[threadIdx.x] = rW1[threadIdx.x] + rW2[threadIdx.x];
    }
    __syncthreads();

    int nid = blockIdx.x * 256 + threadIdx.x;
    if (nid >= n) return;

    float xv[F];
    const float4* xp = (const float4*)(x + (size_t)nid * F);
    #pragma unroll
    for (int q = 0; q < F / 4; q++) {
        float4 v = xp[q];
        xv[q*4+0] = v.x; xv[q*4+1] = v.y; xv[q*4+2] = v.z; xv[q*4+3] = v.w;
    }

    float acc[9];
    #pragma unroll
    for (int k = 0; k < 9; k++) acc[k] = 0.f;

    #pragma unroll
    for (int j = 0; j < F; j++) {
        float4 w0 = *(const float4*)(Wf + j * 8);
        float4 w1 = *(const float4*)(Wf + j * 8 + 4);
        float xj = xv[j];
        acc[0] = fmaf(xj, w0.x, acc[0]);
        acc[1] = fmaf(xj, w0.y, acc[1]);
        acc[2] = fmaf(xj, w0.z, acc[2]);
        acc[3] = fmaf(xj, w0.w, acc[3]);
        acc[4] = fmaf(xj, w1.x, acc[4]);
        acc[5] = fmaf(xj, w1.y, acc[5]);
        acc[6] = fmaf(xj, w1.z, acc[6]);
        acc[7] = fmaf(xj, w1.w, acc[7]);
        acc[8] = fmaf(xj, bv[j], acc[8]);
    }

    float4* gp = (float4*)(g + (size_t)nid * 12);
    gp[0] = make_float4(acc[0], acc[1], acc[2], acc[3]);
    gp[1] = make_float4(acc[4], acc[5], acc[6], acc[7]);
    gp[2] = make_float4(acc[8], 0.f, 0.f, 0.f);

    if (ROOT) {
        float r = rb1[0] + rb2[0];
        #pragma unroll
        for (int j = 0; j < F; j++) r = fmaf(xv[j], wr[j], r);
        out[nid] = r;
    }
}

// ---------------------------------------------------------------------------
// Shared per-edge message computation (both relations, unified index t).
// 1 edge per thread per iteration — proven-coalesced access pattern (R3).
// ---------------------------------------------------------------------------
__device__ __forceinline__ void edge_msg(
    int t,
    const int* __restrict__ src1, const int* __restrict__ dst1,
    const float* __restrict__ ea1, const float* __restrict__ g1,
    const int* __restrict__ src2, const int* __restrict__ dst2,
    const float* __restrict__ ea2, const float* __restrict__ g2,
    int& d_out, float& m_out)
{
    const int* srcp; const int* dstp; const float* eap; const float* gp;
    int e;
    if (t < E1) { e = t;      srcp = src1; dstp = dst1; eap = ea1; gp = g1; }
    else        { e = t - E1; srcp = src2; dstp = dst2; eap = ea2; gp = g2; }

    int s = srcp[e];
    d_out = dstp[e];
    const float4* ap = (const float4*)(eap + (size_t)e * 8);
    float4 a0 = ap[0];
    float4 a1 = ap[1];
    const float4* gr = (const float4*)(gp + (size_t)s * 12);
    float4 ga = gr[0];
    float4 gb = gr[1];
    float4 gc = gr[2];

    float msg = gc.x;
    msg = fmaf(a0.x, ga.x, msg);
    msg = fmaf(a0.y, ga.y, msg);
    msg = fmaf(a0.z, ga.z, msg);
    msg = fmaf(a0.w, ga.w, msg);
    msg = fmaf(a1.x, gb.x, msg);
    msg = fmaf(a1.y, gb.y, msg);
    msg = fmaf(a1.z, gb.z, msg);
    msg = fmaf(a1.w, gb.w, msg);
    m_out = msg;
}

// ---------------------------------------------------------------------------
// Kernel A: msg compute (coalesced store) + per-WG 128-bucket histogram.
// CHUNK=2048 -> 1954 WGs for occupancy.
// ---------------------------------------------------------------------------
__global__ __launch_bounds__(256) void msg_hist_kernel(
    const int* __restrict__ src1, const int* __restrict__ dst1,
    const float* __restrict__ ea1, const float* __restrict__ g1,
    const int* __restrict__ src2, const int* __restrict__ dst2,
    const float* __restrict__ ea2, const float* __restrict__ g2,
    float* __restrict__ msg_out, int* __restrict__ H)
{
    __shared__ int hist[NB];
    if (threadIdx.x < NB) hist[threadIdx.x] = 0;
    __syncthreads();

    int base = blockIdx.x * CHUNK;
    #pragma unroll
    for (int it = 0; it < CHUNK / 256; ++it) {
        int t = base + it * 256 + threadIdx.x;
        if (t < TOTAL_E) {
            int d; float m;
            edge_msg(t, src1, dst1, ea1, g1, src2, dst2, ea2, g2, d, m);
            msg_out[t] = m;
            atomicAdd(&hist[d >> BSHIFT], 1);
        }
    }
    __syncthreads();
    if (threadIdx.x < NB) H[blockIdx.x * NB + threadIdx.x] = hist[threadIdx.x];
}

// Kernel B: per bucket b, exclusive scan of H[w][b] over w, in place.
// Grid = NB blocks x 256 threads, WPT entries/thread (256*8=2048 >= NWG=1954).
__global__ __launch_bounds__(256) void scan_cols_kernel(int* __restrict__ H,
                                                        int* __restrict__ total)
{
    __shared__ int sums[256];
    int b = blockIdx.x;
    int tid = threadIdx.x;

    int vals[WPT];
    int s = 0;
    #pragma unroll
    for (int k = 0; k < WPT; k++) {
        int w = tid * WPT + k;
        vals[k] = (w < NWG) ? H[w * NB + b] : 0;
        s += vals[k];
    }
    sums[tid] = s;
    __syncthreads();
    for (int off = 1; off < 256; off <<= 1) {
        int t = (tid >= off) ? sums[tid - off] : 0;
        __syncthreads();
        sums[tid] += t;
        __syncthreads();
    }
    int run = sums[tid] - s;
    #pragma unroll
    for (int k = 0; k < WPT; k++) {
        int w = tid * WPT + k;
        if (w < NWG) H[w * NB + b] = run;
        run += vals[k];
    }
    if (tid == 255) total[b] = sums[255];
}

// Kernel C: exclusive scan of 128 bucket totals -> base. 1 block x 128 threads.
__global__ __launch_bounds__(128) void scan_base_kernel(const int* __restrict__ total,
                                                        int* __restrict__ base)
{
    __shared__ int v[NB];
    int tid = threadIdx.x;
    int orig = total[tid];
    v[tid] = orig;
    __syncthreads();
    for (int off = 1; off < NB; off <<= 1) {
        int t = (tid >= off) ? v[tid - off] : 0;
        __syncthreads();
        v[tid] += t;
        __syncthreads();
    }
    base[tid] = v[tid] - orig;
}

// ---------------------------------------------------------------------------
// Kernel E: scatter with full LDS reorder -> coalesced global pair writes
// (runs of ~17 consecutive pairs per bucket; write amplification ~1x).
// ---------------------------------------------------------------------------
__global__ __launch_bounds__(256) void scatter_kernel(
    const int* __restrict__ dst1, const int* __restrict__ dst2,
    const float* __restrict__ msg, const int* __restrict__ H,
    const int* __restrict__ base, uint2* __restrict__ pairs)
{
    __shared__ int cnt[NB];          // counts, then cursors
    __shared__ int sv[NB];           // scan scratch
    __shared__ int gbase[NB];        // global dest base minus local offset
    __shared__ unsigned short bkt[CHUNK];
    __shared__ uint2 lp[CHUNK];      // 16 KB staged pairs

    int tid = threadIdx.x;
    if (tid < NB) cnt[tid] = 0;
    __syncthreads();

    int cbase = blockIdx.x * CHUNK;
    int dloc[CHUNK / 256];
    #pragma unroll
    for (int it = 0; it < CHUNK / 256; ++it) {
        int t = cbase + it * 256 + tid;
        int d = -1;
        if (t < TOTAL_E) {
            d = (t < E1) ? dst1[t] : dst2[t - E1];
            atomicAdd(&cnt[d >> BSHIFT], 1);
        }
        dloc[it] = d;
    }
    __syncthreads();

    // exclusive scan of cnt -> local offsets; build gbase; reset cursors
    int myc = 0;
    if (tid < NB) { myc = cnt[tid]; sv[tid] = myc; }
    __syncthreads();
    for (int off = 1; off < NB; off <<= 1) {
        int t = (tid < NB && tid >= off) ? sv[tid - off] : 0;
        __syncthreads();
        if (tid < NB) sv[tid] += t;
        __syncthreads();
    }
    if (tid < NB) {
        int loff = sv[tid] - myc;
        gbase[tid] = H[blockIdx.x * NB + tid] + base[tid] - loff;
        cnt[tid] = loff;             // cursor starts at local offset
    }
    __syncthreads();

    // placement pass: stage pairs into LDS in bucket-sorted order
    #pragma unroll
    for (int it = 0; it < CHUNK / 256; ++it) {
        int t = cbase + it * 256 + tid;
        if (t < TOTAL_E) {
            int d = dloc[it];
            float m = msg[t];
            int b = d >> BSHIFT;
            int slot = atomicAdd(&cnt[b], 1);
            lp[slot] = make_uint2((unsigned)d, __float_as_uint(m));
            bkt[slot] = (unsigned short)b;
        }
    }
    __syncthreads();

    // coalesced flush: consecutive slots in a bucket -> consecutive global addrs
    int nvalid = TOTAL_E - cbase;
    if (nvalid > CHUNK) nvalid = CHUNK;
    for (int i = tid; i < nvalid; i += 256) {
        int b = bkt[i];
        pairs[gbase[b] + i] = lp[i];
    }
}

// ---------------------------------------------------------------------------
// Kernel F: per-bucket LDS accumulate (4096 fp32), bucket segment split over
// 4 WGs; partial accumulators written to ws. Grid = NBK*4 x 512.
// ---------------------------------------------------------------------------
__global__ __launch_bounds__(512) void reduce_kernel(
    const uint2* __restrict__ pairs, const int* __restrict__ base,
    const int* __restrict__ total, float* __restrict__ part)
{
    __shared__ float acc[4096];
    for (int i = threadIdx.x; i < 4096; i += 512) acc[i] = 0.f;
    __syncthreads();

    int b = blockIdx.x >> 2;
    int k = blockIdx.x & 3;
    int start = base[b];
    int cnt = total[b];
    int q = (cnt + 3) >> 2;
    int s0 = k * q;
    int s1 = s0 + q; if (s1 > cnt) s1 = cnt;

    for (int i = s0 + threadIdx.x; i < s1; i += 512) {
        uint2 p = pairs[start + i];
        atomicAdd(&acc[p.x & 4095], __uint_as_float(p.y));
    }
    __syncthreads();

    float* dp = part + (size_t)blockIdx.x * 4096;
    for (int i = threadIdx.x; i < 4096; i += 512) dp[i] = acc[i];
}

// Kernel G: out[n] += sum of the 4 partials for n's bucket. Root already in out.
__global__ __launch_bounds__(256) void merge_kernel(
    const float* __restrict__ part, float* __restrict__ out)
{
    int n = blockIdx.x * 256 + threadIdx.x;
    if (n < N_I) {
        int b = n >> BSHIFT;
        int i = n & 4095;
        const float* p = part + (size_t)b * 4 * 4096 + i;
        out[n] += (p[0] + p[4096]) + (p[8192] + p[12288]);
    }
}

// ---------------------------------------------------------------------------
// Fallback: round-2 atomic edge kernel (used only if ws too small).
// ---------------------------------------------------------------------------
__global__ __launch_bounds__(256) void edge_kernel_atomic(
    const int* __restrict__ src1, const int* __restrict__ dst1,
    const float* __restrict__ ea1, const float* __restrict__ g1,
    const int* __restrict__ src2, const int* __restrict__ dst2,
    const float* __restrict__ ea2, const float* __restrict__ g2,
    float* __restrict__ out)
{
    int t = blockIdx.x * 256 + threadIdx.x;
    if (t >= TOTAL_E) return;
    int d; float m;
    edge_msg(t, src1, dst1, ea1, g1, src2, dst2, ea2, g2, d, m);
    atomicAdd(out + d, m);
}

extern "C" void kernel_launch(void* const* d_in, const int* in_sizes, int n_in,
                              void* d_out, int out_size, void* d_ws, size_t ws_size,
                              hipStream_t stream) {
    const float* x_i  = (const float*)d_in[0];
    const float* x_h  = (const float*)d_in[1];
    const float* ea_h = (const float*)d_in[2];
    const float* ea_i = (const float*)d_in[3];
    const float* We_h = (const float*)d_in[4];
    const float* be_h = (const float*)d_in[5];
    const float* We_i = (const float*)d_in[6];
    const float* be_i = (const float*)d_in[7];
    const float* Wr_h = (const float*)d_in[8];
    const float* br_h = (const float*)d_in[9];
    const float* Wr_i = (const float*)d_in[10];
    const float* br_i = (const float*)d_in[11];
    const int* src_h = (const int*)d_in[12];
    const int* dst_h = (const int*)d_in[13];
    const int* src_i = (const int*)d_in[14];
    const int* dst_i = (const int*)d_in[15];

    float* out = (float*)d_out;

    // workspace layout with aliasing:
    //   [0, 33.6 MB): g_i + g_h  (dead after msg_hist) -> pairs (32 MB) reuses it
    //   [33.6, 49.6 MB): msg (dead after scatter) -> partials (8.06 MB) reuses it
    char* ws = (char*)d_ws;
    float* g_i   = (float*)ws;                       // 24,000,000 B
    float* g_h   = (float*)(ws + 24000000);          //  9,600,000 B
    uint2* pairs = (uint2*)ws;                       // 32,000,000 B (aliases g)
    float* msg   = (float*)(ws + 33600000);          // 16,000,000 B
    float* part  = (float*)(ws + 33600000);          //  8,060,928 B (aliases msg)
    int*   H     = (int*)  (ws + 49600000);          //  1,000,448 B (1954*128*4)
    int*   tot   = (int*)  (ws + 50600448);          //    512 B (pad to 2048)
    int*   bas   = (int*)  (ws + 50602496);          //    512 B
    const size_t WS_NEEDED = 50603008;               // ~50.6 MB

    precompute_g<16, false><<<(N_H + 255) / 256, 256, 0, stream>>>(
        x_h, We_h, be_h, g_h, N_H, nullptr, nullptr, nullptr, nullptr, nullptr);
    precompute_g<32, true><<<(N_I + 255) / 256, 256, 0, stream>>>(
        x_i, We_i, be_i, g_i, N_I, Wr_h, Wr_i, br_h, br_i, out);

    if (ws_size >= WS_NEEDED) {
        msg_hist_kernel<<<NWG, 256, 0, stream>>>(
            src_h, dst_h, ea_h, g_h, src_i, dst_i, ea_i, g_i, msg, H);
        scan_cols_kernel<<<NB, 256, 0, stream>>>(H, tot);
        scan_base_kernel<<<1, NB, 0, stream>>>(tot, bas);
        scatter_kernel<<<NWG, 256, 0, stream>>>(
            dst_h, dst_i, msg, H, bas, pairs);
        reduce_kernel<<<NBK * 4, 512, 0, stream>>>(pairs, bas, tot, part);
        merge_kernel<<<(N_I + 255) / 256, 256, 0, stream>>>(part, out);
    } else {
        edge_kernel_atomic<<<(TOTAL_E + 255) / 256, 256, 0, stream>>>(
            src_h, dst_h, ea_h, g_h, src_i, dst_i, ea_i, g_i, out);
    }
}